// Round 1
// baseline (987.026 us; speedup 1.0000x reference)
//
#include <hip/hip_runtime.h>
#include <stdint.h>
#include <stddef.h>

#define NBINS 65536
#define EPSF 2.220446049250313e-16f
#define RTILE 4096

// Order-preserving float->uint32 key: ascending key order == ascending float order.
__device__ __forceinline__ uint32_t f2key(float f) {
    uint32_t u = __float_as_uint(f);
    return (u & 0x80000000u) ? ~u : (u | 0x80000000u);
}
__device__ __forceinline__ float key2f(uint32_t k) {
    uint32_t u = (k & 0x80000000u) ? (k ^ 0x80000000u) : ~k;
    return __uint_as_float(u);
}

// Pass 1: out[i] = x[i,:]@w + b; store sortable key; accumulate sum(out) (f64)
// and "any out <= -eps" flag. One wave per row, grid-stride.
__global__ __launch_bounds__(256) void gemv_kernel(
    const float* __restrict__ x, const float* __restrict__ w,
    const float* __restrict__ bptr, uint32_t* __restrict__ keys,
    int N, int D, double* __restrict__ sum_out, int* __restrict__ bad_flag)
{
    __shared__ float4 w4s[512];  // up to D=2048
    const int tid = threadIdx.x;
    const int nf4 = D >> 2;
    const float4* w4g = (const float4*)w;
    for (int i = tid; i < nf4; i += 256) w4s[i] = w4g[i];
    __syncthreads();

    const int wave = tid >> 6, lane = tid & 63;
    const int gwave0 = blockIdx.x * 4 + wave;
    const int nwaves = gridDim.x * 4;
    const float b0 = bptr[0];

    double lsum = 0.0;
    int lbad = 0;
    for (int row = gwave0; row < N; row += nwaves) {
        const float4* xr = (const float4*)(x + (size_t)row * D);
        float dot = 0.f;
        for (int i = lane; i < nf4; i += 64) {
            float4 a = xr[i];
            float4 bb = w4s[i];
            dot = fmaf(a.x, bb.x, dot);
            dot = fmaf(a.y, bb.y, dot);
            dot = fmaf(a.z, bb.z, dot);
            dot = fmaf(a.w, bb.w, dot);
        }
        #pragma unroll
        for (int off = 32; off > 0; off >>= 1) dot += __shfl_down(dot, off, 64);
        if (lane == 0) {
            float f = dot + b0;
            keys[row] = f2key(f);
            lsum += (double)f;
            lbad |= (f + EPSF > 0.f) ? 0 : 1;
        }
    }

    __shared__ double sd[4];
    __shared__ int si[4];
    if (lane == 0) { sd[wave] = lsum; si[wave] = lbad; }
    __syncthreads();
    if (tid == 0) {
        atomicAdd(sum_out, sd[0] + sd[1] + sd[2] + sd[3]);
        int bd = si[0] | si[1] | si[2] | si[3];
        if (bd) atomicOr(bad_flag, 1);
    }
}

// Pass 2: histogram of high 16 bits of keys.
__global__ __launch_bounds__(256) void hist_kernel(
    const uint32_t* __restrict__ keys, uint32_t* __restrict__ hist, int N)
{
    int i = blockIdx.x * 256 + threadIdx.x;
    if (i < N) atomicAdd(&hist[keys[i] >> 16], 1u);
}

// Pass 3: exclusive prefix sum of hist -> base[NBINS+1]; also copy to cnt.
__global__ __launch_bounds__(1024) void scan_kernel(
    const uint32_t* __restrict__ hist, uint32_t* __restrict__ base,
    uint32_t* __restrict__ cnt)
{
    __shared__ uint32_t partial[1024];
    const int t = threadIdx.x;
    const int per = NBINS / 1024;  // 64
    uint32_t s = 0;
    for (int i = 0; i < per; ++i) s += hist[t * per + i];
    partial[t] = s;
    __syncthreads();
    for (int off = 1; off < 1024; off <<= 1) {
        uint32_t v = (t >= off) ? partial[t - off] : 0u;
        __syncthreads();
        partial[t] += v;
        __syncthreads();
    }
    uint32_t run = (t == 0) ? 0u : partial[t - 1];
    for (int i = 0; i < per; ++i) {
        int idx = t * per + i;
        base[idx] = run;
        cnt[idx] = run;
        run += hist[idx];
    }
    if (t == 1023) base[NBINS] = run;  // == N
}

// Pass 4: scatter keys into bucket-grouped order (order within bucket arbitrary).
__global__ __launch_bounds__(256) void scatter_kernel(
    const uint32_t* __restrict__ keys, uint32_t* __restrict__ cnt,
    uint32_t* __restrict__ sorted, int N)
{
    int i = blockIdx.x * 256 + threadIdx.x;
    if (i < N) {
        uint32_t k = keys[i];
        uint32_t pos = atomicAdd(&cnt[k >> 16], 1u);
        sorted[pos] = k;
    }
}

// Pass 5: one block per bucket; exact within-bucket rank counting.
// contribution_i = (2*(base[b]+lc_i) + eq_i - N) * value_i, summed in f64.
__global__ __launch_bounds__(256) void rank_kernel(
    const uint32_t* __restrict__ sorted, const uint32_t* __restrict__ base,
    int N, double* __restrict__ pairpart)
{
    const int b = blockIdx.x;
    const uint32_t start = base[b], end = base[b + 1];
    const uint32_t m = end - start;
    if (m == 0) return;  // pairpart pre-zeroed

    __shared__ uint32_t tile[RTILE];
    const int tid = threadIdx.x;
    double acc = 0.0;
    const uint32_t rounds = (m + 255u) / 256u;
    for (uint32_t r = 0; r < rounds; ++r) {
        uint32_t p = start + r * 256u + (uint32_t)tid;
        bool active = (p < end);
        uint32_t k = active ? sorted[p] : 0u;
        uint32_t lc = 0, eq = 0;
        for (uint32_t ts = start; ts < end; ts += RTILE) {
            uint32_t tn = end - ts;
            if (tn > RTILE) tn = RTILE;
            __syncthreads();
            for (uint32_t j = (uint32_t)tid; j < tn; j += 256u) tile[j] = sorted[ts + j];
            __syncthreads();
            if (active) {
                for (uint32_t j = 0; j < tn; ++j) {
                    uint32_t kk = tile[j];
                    lc += (kk < k) ? 1u : 0u;
                    eq += (kk == k) ? 1u : 0u;
                }
            }
        }
        if (active) {
            float f = key2f(k);
            double coef = 2.0 * (double)(start + lc) + (double)eq - (double)N;
            acc += coef * (double)f;
        }
    }

    __shared__ double sred[256];
    sred[tid] = acc;
    __syncthreads();
    for (int off = 128; off > 0; off >>= 1) {
        if (tid < off) sred[tid] += sred[tid + off];
        __syncthreads();
    }
    if (tid == 0) pairpart[b] = sred[0];
}

// Pass 6: reduce per-bucket partials, combine into final outputs.
__global__ __launch_bounds__(1024) void finalize_kernel(
    const double* __restrict__ pairpart, const double* __restrict__ sum_out,
    const int* __restrict__ bad_flag, float* __restrict__ out, int N)
{
    __shared__ double sred[1024];
    const int t = threadIdx.x;
    double s = 0.0;
    for (int i = t; i < NBINS; i += 1024) s += pairpart[i];
    sred[t] = s;
    __syncthreads();
    for (int off = 512; off > 0; off >>= 1) {
        if (t < off) sred[t] += sred[t + off];
        __syncthreads();
    }
    if (t == 0) {
        double loss = -sum_out[0] + (0.1 / (double)N) * sred[0];
        out[0] = (float)loss;
        out[1] = bad_flag[0] ? 0.0f : 1.0f;
    }
}

extern "C" void kernel_launch(void* const* d_in, const int* in_sizes, int n_in,
                              void* d_out, int out_size, void* d_ws, size_t ws_size,
                              hipStream_t stream) {
    (void)n_in; (void)out_size; (void)ws_size;
    const float* x = (const float*)d_in[0];
    const float* w = (const float*)d_in[1];
    const float* b = (const float*)d_in[2];
    float* out = (float*)d_out;
    const int D = in_sizes[1];
    const int N = in_sizes[0] / D;

    // Workspace layout (bytes):
    //  [0, 262144)            hist      (NBINS u32)         -- zeroed
    //  [262144, 786432)       pairpart  (NBINS f64)         -- zeroed
    //  [786432, 786440)       sum_out   (f64)               -- zeroed
    //  [786440, 786444)       bad_flag  (i32)               -- zeroed
    //  [786448, 1048596)      base      (NBINS+1 u32)
    //  [1048600, 1310744)     cnt       (NBINS u32)
    //  [1310744, +4N)         keys      (N u32)
    //  [1310744+4N, +4N)      sorted    (N u32)
    uint8_t* W = (uint8_t*)d_ws;
    uint32_t* hist     = (uint32_t*)(W);
    double*   pairpart = (double*)(W + 262144);
    double*   sum_out  = (double*)(W + 786432);
    int*      bad_flag = (int*)(W + 786440);
    uint32_t* base     = (uint32_t*)(W + 786448);
    uint32_t* cnt      = (uint32_t*)(W + 1048600);
    uint32_t* keys     = (uint32_t*)(W + 1310744);
    uint32_t* sorted   = (uint32_t*)(W + 1310744 + (size_t)N * 4);

    hipMemsetAsync(d_ws, 0, 786448, stream);
    gemv_kernel<<<2048, 256, 0, stream>>>(x, w, b, keys, N, D, sum_out, bad_flag);
    hist_kernel<<<(N + 255) / 256, 256, 0, stream>>>(keys, hist, N);
    scan_kernel<<<1, 1024, 0, stream>>>(hist, base, cnt);
    scatter_kernel<<<(N + 255) / 256, 256, 0, stream>>>(keys, cnt, sorted, N);
    rank_kernel<<<NBINS, 256, 0, stream>>>(sorted, base, N, pairpart);
    finalize_kernel<<<1, 1024, 0, stream>>>(pairpart, sum_out, bad_flag, out, N);
}

// Round 2
// 985.521 us; speedup vs baseline: 1.0015x; 1.0015x over previous
//
#include <hip/hip_runtime.h>
#include <stdint.h>
#include <stddef.h>

#define NBINS 65536
#define EPSF 2.220446049250313e-16f
#define RTILE 4096

// Order-preserving float->uint32 key.
__device__ __forceinline__ uint32_t f2key(float f) {
    uint32_t u = __float_as_uint(f);
    return (u & 0x80000000u) ? ~u : (u | 0x80000000u);
}
__device__ __forceinline__ float key2f(uint32_t k) {
    uint32_t u = (k & 0x80000000u) ? (k ^ 0x80000000u) : ~k;
    return __uint_as_float(u);
}

// Pass 1: out[i] = x[i,:]@w + b; store key; histogram hi-16 bits; accumulate
// sum(out) (f64 atomics) and "any out <= -eps" flag. One wave per CHUNK of rows
// (consecutive rows -> key-store / hist-atomic line locality).
__global__ __launch_bounds__(256) void gemv_kernel(
    const float* __restrict__ x, const float* __restrict__ w,
    const float* __restrict__ bptr, uint32_t* __restrict__ keys,
    uint32_t* __restrict__ hist, int N, int D,
    double* __restrict__ sum_out, int* __restrict__ bad_flag)
{
    __shared__ float4 w4s[512];
    const int tid = threadIdx.x;
    const int nf4 = D >> 2;
    const float4* w4g = (const float4*)w;
    for (int i = tid; i < nf4; i += 256) w4s[i] = w4g[i];
    __syncthreads();

    const int wave = tid >> 6, lane = tid & 63;
    const int gwave = blockIdx.x * 4 + wave;
    const int nwaves = gridDim.x * 4;
    const int rows_per = (N + nwaves - 1) / nwaves;
    const int r0 = gwave * rows_per;
    const int r1 = (r0 + rows_per < N) ? (r0 + rows_per) : N;
    const float b0 = bptr[0];

    double lsum = 0.0;
    int lbad = 0;
    for (int row = r0; row < r1; ++row) {
        const float4* xr = (const float4*)(x + (size_t)row * D);
        float dot = 0.f;
        for (int i = lane; i < nf4; i += 64) {
            float4 a = xr[i];
            float4 bb = w4s[i];
            dot = fmaf(a.x, bb.x, dot);
            dot = fmaf(a.y, bb.y, dot);
            dot = fmaf(a.z, bb.z, dot);
            dot = fmaf(a.w, bb.w, dot);
        }
        #pragma unroll
        for (int off = 32; off > 0; off >>= 1) dot += __shfl_down(dot, off, 64);
        if (lane == 0) {
            float f = dot + b0;
            uint32_t k = f2key(f);
            keys[row] = k;
            atomicAdd(&hist[k >> 16], 1u);
            lsum += (double)f;
            lbad |= (f + EPSF > 0.f) ? 0 : 1;
        }
    }

    __shared__ double sd[4];
    __shared__ int si[4];
    if (lane == 0) { sd[wave] = lsum; si[wave] = lbad; }
    __syncthreads();
    if (tid == 0) {
        atomicAdd(sum_out, sd[0] + sd[1] + sd[2] + sd[3]);
        int bd = si[0] | si[1] | si[2] | si[3];
        if (bd) atomicOr(bad_flag, 1);
    }
}

// Pass 2: exclusive scan of hist -> base[NBINS+1]; copy to cnt; compact
// non-empty bins into nzb[], count into nb_count.
__global__ __launch_bounds__(1024) void scan_kernel(
    const uint32_t* __restrict__ hist, uint32_t* __restrict__ base,
    uint32_t* __restrict__ cnt, uint32_t* __restrict__ nzb,
    int* __restrict__ nb_count)
{
    __shared__ uint32_t partial[1024];
    __shared__ int nb_lds;
    const int t = threadIdx.x;
    if (t == 0) nb_lds = 0;
    const int per = NBINS / 1024;  // 64
    uint32_t s = 0;
    for (int i = 0; i < per; ++i) s += hist[t * per + i];
    partial[t] = s;
    __syncthreads();
    for (int off = 1; off < 1024; off <<= 1) {
        uint32_t v = (t >= off) ? partial[t - off] : 0u;
        __syncthreads();
        partial[t] += v;
        __syncthreads();
    }
    uint32_t run = (t == 0) ? 0u : partial[t - 1];
    for (int i = 0; i < per; ++i) {
        int idx = t * per + i;
        uint32_t h = hist[idx];
        base[idx] = run;
        cnt[idx] = run;
        if (h != 0u) {
            int pos = atomicAdd(&nb_lds, 1);
            nzb[pos] = (uint32_t)idx;
        }
        run += h;
    }
    if (t == 1023) base[NBINS] = run;
    __syncthreads();
    if (t == 0) *nb_count = nb_lds;
}

// Pass 3: scatter keys into bucket-grouped order.
__global__ __launch_bounds__(256) void scatter_kernel(
    const uint32_t* __restrict__ keys, uint32_t* __restrict__ cnt,
    uint32_t* __restrict__ sorted, int N)
{
    int i = blockIdx.x * 256 + threadIdx.x;
    if (i < N) {
        uint32_t k = keys[i];
        uint32_t pos = atomicAdd(&cnt[k >> 16], 1u);
        sorted[pos] = k;
    }
}

// Pass 4: grid-stride over non-empty buckets; exact within-bucket rank count.
// contribution_i = (2*(base[b]+lc_i) + eq_i - N) * v_i, f64. Finalize folded
// in via done-counter.
__global__ __launch_bounds__(256) void rank_kernel(
    const uint32_t* __restrict__ sorted, const uint32_t* __restrict__ base,
    const uint32_t* __restrict__ nzb, const int* __restrict__ nb_count,
    int N, double* __restrict__ pair_acc, const double* __restrict__ sum_out,
    const int* __restrict__ bad_flag, int* __restrict__ done_cnt,
    float* __restrict__ out)
{
    __shared__ uint32_t tile[RTILE];
    __shared__ double sred[256];
    const int tid = threadIdx.x;
    const int nb = *nb_count;
    double acc = 0.0;

    for (int ib = blockIdx.x; ib < nb; ib += gridDim.x) {
        const uint32_t b = nzb[ib];
        const uint32_t start = base[b], end = base[b + 1];
        const uint32_t m = end - start;

        if (m <= RTILE) {
            // Fast path: whole bucket resident in LDS.
            __syncthreads();
            for (uint32_t j = tid; j < m; j += 256u) tile[j] = sorted[start + j];
            __syncthreads();
            const uint32_t rounds = (m + 255u) / 256u;
            for (uint32_t r = 0; r < rounds; ++r) {
                uint32_t p = r * 256u + (uint32_t)tid;
                if (p < m) {
                    uint32_t k = tile[p];
                    uint32_t lc = 0, eq = 0;
                    uint32_t m4 = m & ~3u, j = 0;
                    for (; j < m4; j += 4) {
                        uint4 t4 = *(const uint4*)(tile + j);
                        lc += (t4.x < k); eq += (t4.x == k);
                        lc += (t4.y < k); eq += (t4.y == k);
                        lc += (t4.z < k); eq += (t4.z == k);
                        lc += (t4.w < k); eq += (t4.w == k);
                    }
                    for (; j < m; ++j) {
                        uint32_t kk = tile[j];
                        lc += (kk < k); eq += (kk == k);
                    }
                    double coef = 2.0 * (double)(start + lc) + (double)eq - (double)N;
                    acc += coef * (double)key2f(k);
                }
            }
        } else {
            // General path: tiled passes over the bucket.
            const uint32_t rounds = (m + 255u) / 256u;
            for (uint32_t r = 0; r < rounds; ++r) {
                uint32_t p = start + r * 256u + (uint32_t)tid;
                bool active = (p < end);
                uint32_t k = active ? sorted[p] : 0u;
                uint32_t lc = 0, eq = 0;
                for (uint32_t ts = start; ts < end; ts += RTILE) {
                    uint32_t tn = end - ts;
                    if (tn > RTILE) tn = RTILE;
                    __syncthreads();
                    for (uint32_t j = tid; j < tn; j += 256u) tile[j] = sorted[ts + j];
                    __syncthreads();
                    if (active) {
                        for (uint32_t j = 0; j < tn; ++j) {
                            uint32_t kk = tile[j];
                            lc += (kk < k); eq += (kk == k);
                        }
                    }
                }
                if (active) {
                    double coef = 2.0 * (double)(start + lc) + (double)eq - (double)N;
                    acc += coef * (double)key2f(k);
                }
            }
        }
    }

    // Block reduction of acc -> one f64 atomic.
    sred[tid] = acc;
    __syncthreads();
    for (int off = 128; off > 0; off >>= 1) {
        if (tid < off) sred[tid] += sred[tid + off];
        __syncthreads();
    }
    if (tid == 0) {
        if (sred[0] != 0.0) atomicAdd(pair_acc, sred[0]);
        __threadfence();
        int d = atomicAdd(done_cnt, 1);
        if (d == (int)gridDim.x - 1) {
            __threadfence();
            double pp = __longlong_as_double(
                atomicAdd((unsigned long long*)pair_acc, 0ULL));
            double so = __longlong_as_double(
                atomicAdd((unsigned long long*)const_cast<double*>(sum_out), 0ULL));
            int bd = atomicAdd(const_cast<int*>(bad_flag), 0);
            double loss = -so + (0.1 / (double)N) * pp;
            out[0] = (float)loss;
            out[1] = bd ? 0.0f : 1.0f;
        }
    }
}

extern "C" void kernel_launch(void* const* d_in, const int* in_sizes, int n_in,
                              void* d_out, int out_size, void* d_ws, size_t ws_size,
                              hipStream_t stream) {
    (void)n_in; (void)out_size; (void)ws_size;
    const float* x = (const float*)d_in[0];
    const float* w = (const float*)d_in[1];
    const float* b = (const float*)d_in[2];
    float* out = (float*)d_out;
    const int D = in_sizes[1];
    const int N = in_sizes[0] / D;

    // Workspace layout (bytes):
    //  [0, 262144)          hist (NBINS u32)       -- zeroed
    //  [262144, 262152)     sum_out (f64)          -- zeroed
    //  [262152, 262160)     pair_acc (f64)         -- zeroed
    //  [262160, 262164)     bad_flag (i32)         -- zeroed
    //  [262164, 262168)     done_cnt (i32)         -- zeroed
    //  [262168, 262172)     nb_count (i32)         -- zeroed
    //  [262176, 524324)     base (NBINS+1 u32)
    //  [524336, 786480)     cnt  (NBINS u32)
    //  [786480, 1048624)    nzb  (NBINS u32)
    //  [1048624, +4N)       keys (N u32)
    //  [1048624+4N, +4N)    sorted (N u32)
    uint8_t* W = (uint8_t*)d_ws;
    uint32_t* hist     = (uint32_t*)(W);
    double*   sum_out  = (double*)(W + 262144);
    double*   pair_acc = (double*)(W + 262152);
    int*      bad_flag = (int*)(W + 262160);
    int*      done_cnt = (int*)(W + 262164);
    int*      nb_count = (int*)(W + 262168);
    uint32_t* base     = (uint32_t*)(W + 262176);
    uint32_t* cnt      = (uint32_t*)(W + 524336);
    uint32_t* nzb      = (uint32_t*)(W + 786480);
    uint32_t* keys     = (uint32_t*)(W + 1048624);
    uint32_t* sorted   = keys + N;

    hipMemsetAsync(d_ws, 0, 262176, stream);
    gemv_kernel<<<2048, 256, 0, stream>>>(x, w, b, keys, hist, N, D, sum_out, bad_flag);
    scan_kernel<<<1, 1024, 0, stream>>>(hist, base, cnt, nzb, nb_count);
    scatter_kernel<<<(N + 255) / 256, 256, 0, stream>>>(keys, cnt, sorted, N);
    rank_kernel<<<2048, 256, 0, stream>>>(sorted, base, nzb, nb_count, N,
                                          pair_acc, sum_out, bad_flag, done_cnt, out);
}

// Round 3
// 841.684 us; speedup vs baseline: 1.1727x; 1.1709x over previous
//
#include <hip/hip_runtime.h>
#include <stdint.h>
#include <stddef.h>

#define NBINS 65536
#define EPSF 2.220446049250313e-16f
#define RTILE 4096

// Order-preserving float->uint32 key.
__device__ __forceinline__ uint32_t f2key(float f) {
    uint32_t u = __float_as_uint(f);
    return (u & 0x80000000u) ? ~u : (u | 0x80000000u);
}
__device__ __forceinline__ float key2f(uint32_t k) {
    uint32_t u = (k & 0x80000000u) ? (k ^ 0x80000000u) : ~k;
    return __uint_as_float(u);
}

// Pass 1: out[i] = x[i,:]@w + b; store key; fine hist (hi-16) via global
// atomics; coarse hist (hi-8) via LDS pre-merge (avoids same-address L2
// atomic serialization on ~16 hot coarse bins); accumulate sum(out) (f64)
// and "any out <= -eps" flag.
__global__ __launch_bounds__(256) void gemv_kernel(
    const float* __restrict__ x, const float* __restrict__ w,
    const float* __restrict__ bptr, uint32_t* __restrict__ keys,
    uint32_t* __restrict__ hist, uint32_t* __restrict__ coarse,
    int N, int D, double* __restrict__ sum_out, int* __restrict__ bad_flag)
{
    __shared__ float4 w4s[512];
    __shared__ uint32_t ch[256];
    const int tid = threadIdx.x;
    const int nf4 = D >> 2;
    const float4* w4g = (const float4*)w;
    for (int i = tid; i < nf4; i += 256) w4s[i] = w4g[i];
    ch[tid] = 0u;
    __syncthreads();

    const int wave = tid >> 6, lane = tid & 63;
    const int gwave = blockIdx.x * 4 + wave;
    const int nwaves = gridDim.x * 4;
    const int rows_per = (N + nwaves - 1) / nwaves;
    const int r0 = gwave * rows_per;
    const int r1 = (r0 + rows_per < N) ? (r0 + rows_per) : N;
    const float b0 = bptr[0];

    double lsum = 0.0;
    int lbad = 0;
    for (int row = r0; row < r1; ++row) {
        const float4* xr = (const float4*)(x + (size_t)row * D);
        float dot = 0.f;
        for (int i = lane; i < nf4; i += 64) {
            float4 a = xr[i];
            float4 bb = w4s[i];
            dot = fmaf(a.x, bb.x, dot);
            dot = fmaf(a.y, bb.y, dot);
            dot = fmaf(a.z, bb.z, dot);
            dot = fmaf(a.w, bb.w, dot);
        }
        #pragma unroll
        for (int off = 32; off > 0; off >>= 1) dot += __shfl_down(dot, off, 64);
        if (lane == 0) {
            float f = dot + b0;
            uint32_t k = f2key(f);
            keys[row] = k;
            atomicAdd(&hist[k >> 16], 1u);
            atomicAdd(&ch[k >> 24], 1u);
            lsum += (double)f;
            lbad |= (f + EPSF > 0.f) ? 0 : 1;
        }
    }

    __shared__ double sd[4];
    __shared__ int si[4];
    if (lane == 0) { sd[wave] = lsum; si[wave] = lbad; }
    __syncthreads();
    if (ch[tid]) atomicAdd(&coarse[tid], ch[tid]);
    if (tid == 0) {
        atomicAdd(sum_out, sd[0] + sd[1] + sd[2] + sd[3]);
        int bd = si[0] | si[1] | si[2] | si[3];
        if (bd) atomicOr(bad_flag, 1);
    }
}

// Pass 2: 256 blocks; block j handles bins [256j, 256j+256).
// Chunk base = sum(coarse[0..j)) (coarse bin j == fine bins [256j,256j+256)).
// LDS exclusive scan of the 256 fine bins; write base/cnt; compact non-empty.
__global__ __launch_bounds__(256) void scan_kernel(
    const uint32_t* __restrict__ hist, const uint32_t* __restrict__ coarse,
    uint32_t* __restrict__ base, uint32_t* __restrict__ cnt,
    uint32_t* __restrict__ nzb, int* __restrict__ nb_count)
{
    __shared__ uint32_t red[256];
    __shared__ uint32_t s[256];
    const int t = threadIdx.x;
    const int j = blockIdx.x;
    const int g = j * 256 + t;

    // Chunk base: reduce coarse[0..j).
    red[t] = (t < j) ? coarse[t] : 0u;
    __syncthreads();
    for (int off = 128; off > 0; off >>= 1) {
        if (t < off) red[t] += red[t + off];
        __syncthreads();
    }
    const uint32_t cb = red[0];

    // Inclusive scan of this chunk's 256 bins.
    const uint32_t h = hist[g];
    s[t] = h;
    __syncthreads();
    for (int off = 1; off < 256; off <<= 1) {
        uint32_t v = (t >= off) ? s[t - off] : 0u;
        __syncthreads();
        s[t] += v;
        __syncthreads();
    }
    const uint32_t excl = cb + s[t] - h;
    base[g] = excl;
    cnt[g] = excl;
    if (h) {
        int pos = atomicAdd(nb_count, 1);
        nzb[pos] = (uint32_t)g;
    }
    if (g == NBINS - 1) base[NBINS] = excl + h;  // == N
}

// Pass 3: scatter keys into bucket-grouped order.
__global__ __launch_bounds__(256) void scatter_kernel(
    const uint32_t* __restrict__ keys, uint32_t* __restrict__ cnt,
    uint32_t* __restrict__ sorted, int N)
{
    int i = blockIdx.x * 256 + threadIdx.x;
    if (i < N) {
        uint32_t k = keys[i];
        uint32_t pos = atomicAdd(&cnt[k >> 16], 1u);
        sorted[pos] = k;
    }
}

// Pass 4: grid-stride over non-empty buckets; exact within-bucket rank count.
// contribution_i = (2*(base[b]+lc_i) + eq_i - N) * v_i, f64. Finalize folded
// in via done-counter.
__global__ __launch_bounds__(256) void rank_kernel(
    const uint32_t* __restrict__ sorted, const uint32_t* __restrict__ base,
    const uint32_t* __restrict__ nzb, const int* __restrict__ nb_count,
    int N, double* __restrict__ pair_acc, const double* __restrict__ sum_out,
    const int* __restrict__ bad_flag, int* __restrict__ done_cnt,
    float* __restrict__ out)
{
    __shared__ uint32_t tile[RTILE];
    __shared__ double sred[256];
    const int tid = threadIdx.x;
    const int nb = *nb_count;
    double acc = 0.0;

    for (int ib = blockIdx.x; ib < nb; ib += gridDim.x) {
        const uint32_t b = nzb[ib];
        const uint32_t start = base[b], end = base[b + 1];
        const uint32_t m = end - start;

        if (m <= RTILE) {
            // Fast path: whole bucket resident in LDS.
            __syncthreads();
            for (uint32_t j = tid; j < m; j += 256u) tile[j] = sorted[start + j];
            __syncthreads();
            const uint32_t rounds = (m + 255u) / 256u;
            for (uint32_t r = 0; r < rounds; ++r) {
                uint32_t p = r * 256u + (uint32_t)tid;
                if (p < m) {
                    uint32_t k = tile[p];
                    uint32_t lc = 0, eq = 0;
                    uint32_t m4 = m & ~3u, j = 0;
                    for (; j < m4; j += 4) {
                        uint4 t4 = *(const uint4*)(tile + j);
                        lc += (t4.x < k); eq += (t4.x == k);
                        lc += (t4.y < k); eq += (t4.y == k);
                        lc += (t4.z < k); eq += (t4.z == k);
                        lc += (t4.w < k); eq += (t4.w == k);
                    }
                    for (; j < m; ++j) {
                        uint32_t kk = tile[j];
                        lc += (kk < k); eq += (kk == k);
                    }
                    double coef = 2.0 * (double)(start + lc) + (double)eq - (double)N;
                    acc += coef * (double)key2f(k);
                }
            }
        } else {
            // General path: tiled passes over the bucket.
            const uint32_t rounds = (m + 255u) / 256u;
            for (uint32_t r = 0; r < rounds; ++r) {
                uint32_t p = start + r * 256u + (uint32_t)tid;
                bool active = (p < end);
                uint32_t k = active ? sorted[p] : 0u;
                uint32_t lc = 0, eq = 0;
                for (uint32_t ts = start; ts < end; ts += RTILE) {
                    uint32_t tn = end - ts;
                    if (tn > RTILE) tn = RTILE;
                    __syncthreads();
                    for (uint32_t j = tid; j < tn; j += 256u) tile[j] = sorted[ts + j];
                    __syncthreads();
                    if (active) {
                        for (uint32_t j = 0; j < tn; ++j) {
                            uint32_t kk = tile[j];
                            lc += (kk < k); eq += (kk == k);
                        }
                    }
                }
                if (active) {
                    double coef = 2.0 * (double)(start + lc) + (double)eq - (double)N;
                    acc += coef * (double)key2f(k);
                }
            }
        }
    }

    // Block reduction of acc -> one f64 atomic.
    sred[tid] = acc;
    __syncthreads();
    for (int off = 128; off > 0; off >>= 1) {
        if (tid < off) sred[tid] += sred[tid + off];
        __syncthreads();
    }
    if (tid == 0) {
        if (sred[0] != 0.0) atomicAdd(pair_acc, sred[0]);
        __threadfence();
        int d = atomicAdd(done_cnt, 1);
        if (d == (int)gridDim.x - 1) {
            __threadfence();
            double pp = __longlong_as_double(
                atomicAdd((unsigned long long*)pair_acc, 0ULL));
            double so = __longlong_as_double(
                atomicAdd((unsigned long long*)const_cast<double*>(sum_out), 0ULL));
            int bd = atomicAdd(const_cast<int*>(bad_flag), 0);
            double loss = -so + (0.1 / (double)N) * pp;
            out[0] = (float)loss;
            out[1] = bd ? 0.0f : 1.0f;
        }
    }
}

extern "C" void kernel_launch(void* const* d_in, const int* in_sizes, int n_in,
                              void* d_out, int out_size, void* d_ws, size_t ws_size,
                              hipStream_t stream) {
    (void)n_in; (void)out_size; (void)ws_size;
    const float* x = (const float*)d_in[0];
    const float* w = (const float*)d_in[1];
    const float* b = (const float*)d_in[2];
    float* out = (float*)d_out;
    const int D = in_sizes[1];
    const int N = in_sizes[0] / D;

    // Workspace layout (bytes):
    //  [0, 262144)          hist   (NBINS u32)     -- zeroed
    //  [262144, 263168)     coarse (256 u32)       -- zeroed
    //  [263168, 263176)     sum_out (f64)          -- zeroed
    //  [263176, 263184)     pair_acc (f64)         -- zeroed
    //  [263184, 263188)     bad_flag (i32)         -- zeroed
    //  [263188, 263192)     done_cnt (i32)         -- zeroed
    //  [263192, 263196)     nb_count (i32)         -- zeroed
    //  [263200, 525348)     base (NBINS+1 u32)
    //  [525352, 787496)     cnt  (NBINS u32)
    //  [787496, 1049640)    nzb  (NBINS u32)
    //  [1049640, +4N)       keys (N u32)
    //  [1049640+4N, +4N)    sorted (N u32)
    uint8_t* W = (uint8_t*)d_ws;
    uint32_t* hist     = (uint32_t*)(W);
    uint32_t* coarse   = (uint32_t*)(W + 262144);
    double*   sum_out  = (double*)(W + 263168);
    double*   pair_acc = (double*)(W + 263176);
    int*      bad_flag = (int*)(W + 263184);
    int*      done_cnt = (int*)(W + 263188);
    int*      nb_count = (int*)(W + 263192);
    uint32_t* base     = (uint32_t*)(W + 263200);
    uint32_t* cnt      = (uint32_t*)(W + 525352);
    uint32_t* nzb      = (uint32_t*)(W + 787496);
    uint32_t* keys     = (uint32_t*)(W + 1049640);
    uint32_t* sorted   = keys + N;

    hipMemsetAsync(d_ws, 0, 263200, stream);
    gemv_kernel<<<2048, 256, 0, stream>>>(x, w, b, keys, hist, coarse, N, D,
                                          sum_out, bad_flag);
    scan_kernel<<<256, 256, 0, stream>>>(hist, coarse, base, cnt, nzb, nb_count);
    scatter_kernel<<<(N + 255) / 256, 256, 0, stream>>>(keys, cnt, sorted, N);
    rank_kernel<<<2048, 256, 0, stream>>>(sorted, base, nzb, nb_count, N,
                                          pair_acc, sum_out, bad_flag, done_cnt, out);
}